// Round 12
// baseline (11119.147 us; speedup 1.0000x reference)
//
#include <hip/hip_runtime.h>
#include <hip/hip_fp16.h>
#include <math.h>

#define BB 8
#define TT 12
#define NN 716
#define EE 10
#define HH 64
#define DIN 65
#define OG 128
#define OU 64
#define XSP 68     // xs row stride
#define NI4 17     // ceil(DIN/4)
#define NT 64      // n-tile per mega block
#define NCB 12     // 12*64 = 768 >= 716
#define NVT 768    // SoA nv stride

// smem float offsets (51.2 KB total)
#define NVS_OFF 0        // nvsT [10][768] = 7680
#define DLS_OFF 7680     // dls  [768]
#define XSS_OFF 8448     // xss  [32][68] = 2176
#define GS_OFF  10624    // gs   [32][68] = 2176
#define SM_TOT  12800
// overlays (valid after j-chunk loop)
#define XG2_OFF 0        // xg2s [64][68] = 4352
#define XST_OFF 4352     // xst  [64][68] = 4352 (overwrites dls/xss)
#define H1_OFF  8704     // h1s  [64][16]
#define H2_OFF  9728     // h2s  [64][2]

__device__ __forceinline__ float sigmf(float x){ return 1.0f/(1.0f+__expf(-x)); }

// ---------------- emb precompute + cur0 ----------------
__global__ void k_emb(const float* __restrict__ src, const float* __restrict__ ne,
                      const float* __restrict__ te, const float* __restrict__ de,
                      float* __restrict__ emb, float* __restrict__ cur){
  int idx = blockIdx.x*256 + threadIdx.x;
  if (idx >= BB*TT*NN) return;
  int n = idx % NN; int t = (idx/NN) % TT; int b = idx/(NN*TT);
  const float* s = src + (size_t)idx*3;
  float x = s[0];
  int ti = (int)(s[1]*288.0f);
  int di = (int)(s[2]);
  size_t eo = ((size_t)b*TT + t)*NN*EE + (size_t)n*EE;
  #pragma unroll
  for (int e=0;e<EE;e++)
    emb[eo+e] = ne[n*EE+e]*te[ti*EE+e]*de[di*EE+e];
  cur[((size_t)t*BB + b)*NN + n] = x;   // cur[0][t][b][n]
}

// ---------------- per-layer prep: w4->fp16 (z=0 gate / z=1 update) + misc (z=2) ----------------
__global__ __launch_bounds__(256) void k_prep_all(
    const float* __restrict__ ne, const float* __restrict__ wp_g,
    const float* __restrict__ wp_u, __half* __restrict__ wg4,
    __half* __restrict__ wu4,
    const float* __restrict__ bp_g, const float* __restrict__ bp_u,
    float* __restrict__ bg, float* __restrict__ bu,
    float* __restrict__ h, const float* __restrict__ cur_c,
    const float* __restrict__ f1W, const float* __restrict__ f1b,
    const float* __restrict__ f2W, const float* __restrict__ f2b,
    const float* __restrict__ f3W, const float* __restrict__ f3b,
    const float* __restrict__ emb,
    float* __restrict__ xsg, float* __restrict__ nv)
{
  __shared__ float wps[EE*4*OG];
  int z = blockIdx.z;
  int tid = threadIdx.x;
  if (z < 2){
    const float* wp = z ? wp_u : wp_g;
    __half* w4 = z ? wu4 : wg4;
    int O = z ? OU : OG;
    int ki4 = blockIdx.x;          // 0..33 : k*17+i4
    int nq  = blockIdx.y;          // 0..3
    int k = ki4/NI4, i4 = ki4 - k*NI4;
    for (int idx=tid; idx<EE*4*O; idx+=256){
      int e = idx/(4*O); int rem = idx - e*4*O; int sub = rem/O; int o = rem - sub*O;
      int i = i4*4 + sub;
      wps[idx] = (i<DIN) ? wp[(((size_t)e*2+k)*DIN+i)*O + o] : 0.f;
    }
    __syncthreads();
    int NG = 256/O;
    int o = tid & (O-1), ng = tid / O;
    int n1 = nq*179, n2 = min(NN, n1+179);
    for (int n = n1+ng; n < n2; n += NG){
      float4 a = {0.f,0.f,0.f,0.f};
      #pragma unroll
      for (int e=0;e<EE;e++){
        float nef = ne[n*EE+e];
        a.x += nef*wps[e*4*O + 0*O + o];
        a.y += nef*wps[e*4*O + 1*O + o];
        a.z += nef*wps[e*4*O + 2*O + o];
        a.w += nef*wps[e*4*O + 3*O + o];
      }
      uint2 pack;
      __half* ph = (__half*)&pack;
      ph[0]=__float2half(a.x); ph[1]=__float2half(a.y);
      ph[2]=__float2half(a.z); ph[3]=__float2half(a.w);
      ((uint2*)w4)[((size_t)(n*2+k)*NI4 + i4)*O + o] = pack;
    }
  } else {
    int mt = (blockIdx.x*4 + blockIdx.y)*256 + tid;
    const int MT = 136*256;
    for (int i=mt; i<BB*NN*HH; i+=MT) h[i] = 0.f;
    for (int i=mt; i<NN*OG; i+=MT){
      int o=i&(OG-1), n=i>>7; float a=0.f;
      #pragma unroll
      for (int e=0;e<EE;e++) a += ne[n*EE+e]*bp_g[e*OG+o];
      bg[i]=a;
    }
    for (int i=mt; i<NN*OU; i+=MT){
      int o=i&(OU-1), n=i>>6; float a=0.f;
      #pragma unroll
      for (int e=0;e<EE;e++) a += ne[n*EE+e]*bp_u[e*OU+o];
      bu[i]=a;
    }
    for (int idx=mt; idx<BB*NN; idx+=MT){
      int b=idx/NN, n=idx-b*NN;
      float x = cur_c[(size_t)b*NN + n];   // t = 0
      float* xr = xsg + (size_t)idx*XSP;
      xr[0]=x;
      #pragma unroll
      for (int i2=1;i2<XSP;i2++) xr[i2]=0.f;
      float h1[16];
      #pragma unroll
      for (int k=0;k<16;k++) h1[k]=sigmf(f1b[k]+f1W[k*DIN]*x);
      float h2[2];
      #pragma unroll
      for (int k=0;k<2;k++){
        float s=f2b[k];
        #pragma unroll
        for (int q=0;q<16;q++) s+=f2W[k*16+q]*h1[q];
        h2[k]=sigmf(s);
      }
      #pragma unroll
      for (int e=0;e<EE;e++){
        float xe=f3b[e]+f3W[e*2]*h2[0]+f3W[e*2+1]*h2[1];
        nv[(size_t)idx*EE+e]=tanhf(emb[(((size_t)b*TT+0)*NN+n)*EE+e]*xe);
      }
    }
  }
}

// ======== shared device phases for mega kernels ========

// P0+P1+P2: stage nv SoA, full in-block d, j-chunk xg2 accumulation.
// Leaves xg2s/xst ready for the transform. acc result written into xg2s (d_n folded),
// xst staged from xsrows (cols<=64, pad 0).
__device__ __forceinline__ void mega_front(
    const float* __restrict__ nvin, const float* __restrict__ xsrows,
    int b, int n0, int tid, float* sm)
{
  float* nvsT = sm + NVS_OFF;
  float* dls  = sm + DLS_OFF;
  float (*xss)[XSP] = (float(*)[XSP])(sm + XSS_OFF);
  float (*gs)[XSP]  = (float(*)[XSP])(sm + GS_OFF);
  float (*xg2s)[XSP] = (float(*)[XSP])(sm + XG2_OFF);
  float (*xst)[XSP]  = (float(*)[XSP])(sm + XST_OFF);
  // ---- P0: stage nv[b] -> SoA, pad zeros
  {
    const float* nvb = nvin + (size_t)b*NN*EE;
    for (int idx=tid; idx<NN*EE; idx+=512){
      int n = idx/EE, e = idx - n*EE;
      nvsT[e*NVT + n] = nvb[idx];
    }
    for (int idx=tid; idx<EE*(NVT-NN); idx+=512){
      int e = idx/(NVT-NN), n = NN + (idx - e*(NVT-NN));
      nvsT[e*NVT + n] = 0.f;
    }
    if (tid < NVT-NN) dls[NN+tid] = 0.f;
  }
  __syncthreads();
  // ---- P1: full d[b][:] in-block (32 groups x 16 lanes, 4 j's per group per pass)
  {
    int grp = tid>>4, ln = tid&15;
    for (int kk=0; kk<6; ++kk){
      int jb = grp*4 + kk*128;           // <= 764
      float bv4[4][EE];
      #pragma unroll
      for (int r=0;r<4;r++)
        #pragma unroll
        for (int e=0;e<EE;e++) bv4[r][e] = nvsT[e*NVT + jb + r];
      float s4[4] = {0.f,0.f,0.f,0.f};
      for (int n=ln; n<NN; n+=16){
        float av[EE];
        #pragma unroll
        for (int e=0;e<EE;e++) av[e] = nvsT[e*NVT+n];
        #pragma unroll
        for (int r=0;r<4;r++){
          float dot=0.f;
          #pragma unroll
          for (int e=0;e<EE;e++) dot += bv4[r][e]*av[e];
          s4[r] += fmaxf(dot,0.f);
        }
      }
      #pragma unroll
      for (int r=0;r<4;r++){
        float s = s4[r];
        s += __shfl_xor(s,1,64); s += __shfl_xor(s,2,64);
        s += __shfl_xor(s,4,64); s += __shfl_xor(s,8,64);
        if (ln==0){
          int j = jb + r;
          if (j < NN) dls[j] = rsqrtf(s);
        }
      }
    }
  }
  __syncthreads();
  // ---- P2: j-chunk loop, G on the fly (d_j folded), acc in regs
  int nl = tid>>3, ig = tid&7;
  float acc[8]; float a64 = 0.f;
  #pragma unroll
  for (int s=0;s<8;s++) acc[s]=0.f;
  for (int jc=0; jc<NN; jc+=32){
    __syncthreads();
    for (int idx=tid; idx<32*XSP; idx+=512){
      int r = idx/XSP, ii = idx - r*XSP;
      int j = jc + r;
      float v = 0.f;
      if (j < NN && ii <= 64) v = xsrows[((size_t)b*NN+j)*XSP + ii];
      xss[r][ii] = v;
    }
    {
      int jg = tid>>4, ngrp = tid&15;
      int j = jc + jg;                 // < 768, pad-safe
      float bvv[EE];
      #pragma unroll
      for (int e=0;e<EE;e++) bvv[e] = nvsT[e*NVT+j];
      float dlj = dls[j];              // 0 for j>=NN
      #pragma unroll
      for (int s=0;s<4;s++){
        int n = n0 + ngrp*4 + s;
        float dot=0.f;
        #pragma unroll
        for (int e=0;e<EE;e++) dot += bvv[e]*nvsT[e*NVT+n];
        gs[jg][ngrp*4+s] = fmaxf(dot,0.f)*dlj;
      }
    }
    __syncthreads();
    #pragma unroll 4
    for (int jj=0; jj<32; ++jj){
      float g = gs[jj][nl];
      float4 xa = *(const float4*)&xss[jj][ig*8];
      float4 xb = *(const float4*)&xss[jj][ig*8+4];
      acc[0]+=g*xa.x; acc[1]+=g*xa.y; acc[2]+=g*xa.z; acc[3]+=g*xa.w;
      acc[4]+=g*xb.x; acc[5]+=g*xb.y; acc[6]+=g*xb.z; acc[7]+=g*xb.w;
      if (ig==0) a64 += g*xss[jj][64];
    }
  }
  __syncthreads();
  // ---- dump xg2 (reads dls; xg2s region disjoint from dls)
  {
    float dn = dls[n0 + nl];
    #pragma unroll
    for (int s=0;s<8;s++) xg2s[nl][ig*8+s] = acc[s]*dn;
    if (ig==0) xg2s[nl][64] = a64*dn;
    if (ig==7){ xg2s[nl][65]=0.f; xg2s[nl][66]=0.f; xg2s[nl][67]=0.f; }
  }
  __syncthreads();
  // ---- stage xst (overwrites dls/xss region; both dead)
  for (int idx=tid; idx<NT*XSP; idx+=512){
    int r = idx/XSP, ii = idx - r*XSP;
    int n = n0 + r;
    float v = 0.f;
    if (n < NN && ii <= 64) v = xsrows[((size_t)b*NN+n)*XSP + ii];
    xst[r][ii] = v;
  }
  __syncthreads();
}

// ---------------- mega gate: xg2 + gate transform + update-MLP -> nv_u ----------------
__global__ __launch_bounds__(512) void k_mega_gate(
    const float* __restrict__ nvin, const float* __restrict__ xsg,
    const __half* __restrict__ wg, const float* __restrict__ bg,
    const float* __restrict__ h, const float* __restrict__ cur_ct,
    const float* __restrict__ emb, int t,
    const float* __restrict__ f1W, const float* __restrict__ f1b,
    const float* __restrict__ f2W, const float* __restrict__ f2b,
    const float* __restrict__ f3W, const float* __restrict__ f3b,
    float* __restrict__ rbuf, float* __restrict__ xsu,
    float* __restrict__ nvout)
{
  __shared__ __align__(16) float sm[SM_TOT];
  int nc = blockIdx.x, b = blockIdx.y;
  int tid = threadIdx.x;
  int n0 = nc*NT;
  mega_front(nvin, xsg, b, n0, tid, sm);
  float (*xg2s)[XSP] = (float(*)[XSP])(sm + XG2_OFF);
  float (*xst)[XSP]  = (float(*)[XSP])(sm + XST_OFF);
  float (*h1s)[16]   = (float(*)[16])(sm + H1_OFF);
  float (*h2s)[2]    = (float(*)[2])(sm + H2_OFF);
  // ---- phase B: gate GEMV (O=128), fp16 weights
  int o = tid & 127, q = tid >> 7;
  float candv[16];
  {
    const uint2* wbase = (const uint2*)wg;
    for (int k=0;k<16;k++){
      int nlcl = q*16 + k;
      int n = n0 + nlcl;
      candv[k] = 0.f;
      if (n >= NN) continue;
      const uint2* w0p = wbase + ((size_t)(n*2))*NI4*OG + o;
      const uint2* w1p = w0p + (size_t)NI4*OG;
      float acc2 = bg[n*OG+o];
      #pragma unroll 4
      for (int i4=0;i4<NI4;i4++){
        uint2 r0 = w0p[(size_t)i4*OG];
        uint2 r1 = w1p[(size_t)i4*OG];
        const __half* h0 = (const __half*)&r0;
        const __half* h1 = (const __half*)&r1;
        int i = i4*4;
        acc2 += xst[nlcl][i  ]*__half2float(h0[0]) + xst[nlcl][i+1]*__half2float(h0[1])
              + xst[nlcl][i+2]*__half2float(h0[2]) + xst[nlcl][i+3]*__half2float(h0[3])
              + xg2s[nlcl][i  ]*__half2float(h1[0]) + xg2s[nlcl][i+1]*__half2float(h1[1])
              + xg2s[nlcl][i+2]*__half2float(h1[2]) + xg2s[nlcl][i+3]*__half2float(h1[3]);
      }
      float v = sigmf(acc2);
      if (o < 64){
        float cv = v * h[((size_t)b*NN+n)*HH + o];
        xsu[((size_t)b*NN+n)*XSP + 1 + o] = cv;
        candv[k] = cv;
      } else {
        rbuf[((size_t)b*NN+n)*HH + (o-64)] = v;
        if (o == 64){
          float x = cur_ct[(size_t)b*NN+n];
          candv[k] = x;
          xsu[((size_t)b*NN+n)*XSP] = x;
        }
      }
    }
  }
  __syncthreads();
  // write cand rows into xst (cs for MLP)
  for (int k=0;k<16;k++){
    int nlcl = q*16+k;
    if (o < 64) xst[nlcl][1+o] = candv[k];
    else if (o == 64) xst[nlcl][0] = candv[k];
  }
  __syncthreads();
  // ---- phase C: update-gcn small MLP -> nvout
  for (int idx=tid; idx<NT*16; idx+=512){
    int nlcl = idx>>4, kk = idx&15;
    const float* wr = f1W + kk*DIN;
    float s = f1b[kk];
    #pragma unroll
    for (int i=0;i<DIN;i++) s += xst[nlcl][i]*wr[i];
    h1s[nlcl][kk] = sigmf(s);
  }
  __syncthreads();
  if (tid < NT*2){
    int nlcl = tid>>1, kk = tid&1;
    float s = f2b[kk];
    #pragma unroll
    for (int q2=0;q2<16;q2++) s += h1s[nlcl][q2]*f2W[kk*16+q2];
    h2s[nlcl][kk] = sigmf(s);
  }
  __syncthreads();
  for (int idx=tid; idx<NT*EE; idx+=512){
    int nlcl = idx/EE, e = idx - nlcl*EE;
    int n = n0 + nlcl;
    if (n < NN){
      float xe = f3b[e] + f3W[e*2]*h2s[nlcl][0] + f3W[e*2+1]*h2s[nlcl][1];
      nvout[((size_t)b*NN+n)*EE+e] = tanhf(emb[(((size_t)b*TT+t)*NN+n)*EE+e]*xe);
    }
  }
}

// ---------------- mega update: xg2 + GRU update + next-gate-MLP / pred ----------------
__global__ __launch_bounds__(512) void k_mega_upd(
    const float* __restrict__ nvin, const float* __restrict__ xsu,
    const __half* __restrict__ wu, const float* __restrict__ bu,
    const float* __restrict__ rbuf, float* __restrict__ h,
    float* __restrict__ cur, int c, int t,
    const float* __restrict__ emb,
    const float* __restrict__ f1W, const float* __restrict__ f1b,
    const float* __restrict__ f2W, const float* __restrict__ f2b,
    const float* __restrict__ f3W, const float* __restrict__ f3b,
    const float* __restrict__ predW, const float* __restrict__ predB,
    const float* __restrict__ skipW, const float* __restrict__ skipB,
    float* __restrict__ xsg, float* __restrict__ nvout,
    float* __restrict__ out)
{
  __shared__ __align__(16) float sm[SM_TOT];
  int nc = blockIdx.x, b = blockIdx.y;
  int tid = threadIdx.x;
  int n0 = nc*NT;
  mega_front(nvin, xsu, b, n0, tid, sm);
  float (*xg2s)[XSP] = (float(*)[XSP])(sm + XG2_OFF);
  float (*xst)[XSP]  = (float(*)[XSP])(sm + XST_OFF);
  float (*h1s)[16]   = (float(*)[16])(sm + H1_OFF);
  float (*h2s)[2]    = (float(*)[2])(sm + H2_OFF);
  // ---- phase B: update GEMV (O=64), GRU state update
  int o = tid & 63, q = tid >> 6;
  float hv[8];
  {
    const uint2* wbase = (const uint2*)wu;
    for (int k=0;k<8;k++){
      int nlcl = q*8 + k;
      int n = n0 + nlcl;
      hv[k] = 0.f;
      if (n >= NN) continue;
      const uint2* w0p = wbase + ((size_t)(n*2))*NI4*OU + o;
      const uint2* w1p = w0p + (size_t)NI4*OU;
      float acc2 = bu[n*OU+o];
      #pragma unroll 4
      for (int i4=0;i4<NI4;i4++){
        uint2 r0 = w0p[(size_t)i4*OU];
        uint2 r1 = w1p[(size_t)i4*OU];
        const __half* h0 = (const __half*)&r0;
        const __half* h1 = (const __half*)&r1;
        int i = i4*4;
        acc2 += xst[nlcl][i  ]*__half2float(h0[0]) + xst[nlcl][i+1]*__half2float(h0[1])
              + xst[nlcl][i+2]*__half2float(h0[2]) + xst[nlcl][i+3]*__half2float(h0[3])
              + xg2s[nlcl][i  ]*__half2float(h1[0]) + xg2s[nlcl][i+1]*__half2float(h1[1])
              + xg2s[nlcl][i+2]*__half2float(h1[2]) + xg2s[nlcl][i+3]*__half2float(h1[3]);
      }
      float hc = tanhf(acc2);
      float r = rbuf[((size_t)b*NN+n)*HH+o];
      float hold = h[((size_t)b*NN+n)*HH+o];
      float hn = r*hold + (1.f-r)*hc;
      h[((size_t)b*NN+n)*HH+o] = hn;
      hv[k] = hn;
    }
  }
  __syncthreads();
  // write h rows into xst (cs for MLP / pred); build next xsg
  const float* cur_next = cur + ((size_t)c*TT + (t+1))*BB*NN;   // valid only t<TT-1
  for (int k=0;k<8;k++){
    int nlcl = q*8+k;
    int n = n0 + nlcl;
    xst[nlcl][1+o] = hv[k];
    if (n < NN && t < TT-1){
      xsg[((size_t)b*NN+n)*XSP + 1 + o] = hv[k];
      if (o == 0){
        float xn = cur_next[(size_t)b*NN+n];
        xst[nlcl][0] = xn;
        xsg[((size_t)b*NN+n)*XSP] = xn;
      }
    } else if (o == 0){
      xst[nlcl][0] = 0.f;
    }
  }
  __syncthreads();
  if (t < TT-1){
    // ---- phase C: gate-gcn small MLP -> nvout (for t+1)
    for (int idx=tid; idx<NT*16; idx+=512){
      int nlcl = idx>>4, kk = idx&15;
      const float* wr = f1W + kk*DIN;
      float s = f1b[kk];
      #pragma unroll
      for (int i=0;i<DIN;i++) s += xst[nlcl][i]*wr[i];
      h1s[nlcl][kk] = sigmf(s);
    }
    __syncthreads();
    if (tid < NT*2){
      int nlcl = tid>>1, kk = tid&1;
      float s = f2b[kk];
      #pragma unroll
      for (int q2=0;q2<16;q2++) s += h1s[nlcl][q2]*f2W[kk*16+q2];
      h2s[nlcl][kk] = sigmf(s);
    }
    __syncthreads();
    for (int idx=tid; idx<NT*EE; idx+=512){
      int nlcl = idx/EE, e = idx - nlcl*EE;
      int n = n0 + nlcl;
      if (n < NN){
        float xe = f3b[e] + f3W[e*2]*h2s[nlcl][0] + f3W[e*2+1]*h2s[nlcl][1];
        nvout[((size_t)b*NN+n)*EE+e] =
          tanhf(emb[(((size_t)b*TT+(t+1))*NN+n)*EE+e]*xe);
      }
    }
  } else {
    // ---- final step: pred (+ skip & next-layer cur for c==0)
    for (int idx=tid; idx<NT*TT; idx+=512){
      int nlcl = idx/TT, ot = idx - nlcl*TT;
      int n = n0 + nlcl;
      if (n < NN){
        const float* pw = predW + ((size_t)c*TT + ot)*HH;
        float pv = predB[c*TT+ot];
        #pragma unroll
        for (int q2=0;q2<HH;q2++) pv += xst[nlcl][1+q2]*pw[q2];
        size_t oi = ((size_t)b*TT+ot)*NN + n;
        if (c == 0){
          out[oi] = pv;
          const float* sw = skipW + (size_t)ot*HH;
          float sk = skipB[ot];
          #pragma unroll
          for (int q2=0;q2<HH;q2++) sk += xst[nlcl][1+q2]*sw[q2];
          cur[((size_t)(TT+ot)*BB + b)*NN + n] =
              cur[((size_t)ot*BB + b)*NN + n] - sk;
        } else {
          out[oi] += pv;
        }
      }
    }
  }
}

extern "C" void kernel_launch(void* const* d_in, const int* in_sizes, int n_in,
                              void* d_out, int out_size, void* d_ws, size_t ws_size,
                              hipStream_t stream){
  const float* src  = (const float*)d_in[0];
  const float* ne   = (const float*)d_in[1];
  const float* te   = (const float*)d_in[2];
  const float* de   = (const float*)d_in[3];
  const float* wp_g = (const float*)d_in[4];
  const float* bp_g = (const float*)d_in[5];
  const float* f1W_g= (const float*)d_in[6];
  const float* f1b_g= (const float*)d_in[7];
  const float* f2W_g= (const float*)d_in[8];
  const float* f2b_g= (const float*)d_in[9];
  const float* f3W_g= (const float*)d_in[10];
  const float* f3b_g= (const float*)d_in[11];
  const float* wp_u = (const float*)d_in[12];
  const float* bp_u = (const float*)d_in[13];
  const float* f1W_u= (const float*)d_in[14];
  const float* f1b_u= (const float*)d_in[15];
  const float* f2W_u= (const float*)d_in[16];
  const float* f2b_u= (const float*)d_in[17];
  const float* f3W_u= (const float*)d_in[18];
  const float* f3b_u= (const float*)d_in[19];
  const float* predW= (const float*)d_in[20];
  const float* predB= (const float*)d_in[21];
  const float* skipW= (const float*)d_in[22];
  const float* skipB= (const float*)d_in[23];

  float* ws   = (float*)d_ws;
  float* emb  = ws;
  float* cur  = emb  + (size_t)BB*TT*NN*EE;
  float* wgf  = cur  + (size_t)2*TT*BB*NN;               // fp16 region
  float* bg   = wgf  + (size_t)NN*2*NI4*OG*4/2;
  float* wuf  = bg   + (size_t)NN*OG;
  float* bu   = wuf  + (size_t)NN*2*NI4*OU*4/2;
  float* h    = bu   + (size_t)NN*OU;
  float* xsg  = h    + (size_t)BB*NN*HH;
  float* xsu  = xsg  + (size_t)BB*NN*XSP;
  float* nv_g = xsu  + (size_t)BB*NN*XSP;
  float* nv_u = nv_g + (size_t)BB*NN*EE;
  float* rbuf = nv_u + (size_t)BB*NN*EE;
  float* outp = (float*)d_out;
  __half* wg = (__half*)wgf;
  __half* wu = (__half*)wuf;

  k_emb<<<(BB*TT*NN+255)/256, 256, 0, stream>>>(src, ne, te, de, emb, cur);

  for (int c=0;c<2;c++){
    k_prep_all<<<dim3(2*NI4,4,3),256,0,stream>>>(ne,
        wp_g + (size_t)c*EE*2*DIN*OG, wp_u + (size_t)c*EE*2*DIN*OU, wg, wu,
        bp_g + (size_t)c*EE*OG, bp_u + (size_t)c*EE*OU, bg, bu,
        h, cur + (size_t)c*TT*BB*NN,
        f1W_g + c*16*DIN, f1b_g + c*16, f2W_g + c*32, f2b_g + c*2,
        f3W_g + c*EE*2, f3b_g + c*EE, emb, xsg, nv_g);
    for (int t=0;t<TT;t++){
      k_mega_gate<<<dim3(NCB,BB),512,0,stream>>>(nv_g, xsg, wg, bg, h,
          cur + ((size_t)c*TT+t)*BB*NN, emb, t,
          f1W_u + c*16*DIN, f1b_u + c*16, f2W_u + c*32, f2b_u + c*2,
          f3W_u + c*EE*2, f3b_u + c*EE, rbuf, xsu, nv_u);
      k_mega_upd<<<dim3(NCB,BB),512,0,stream>>>(nv_u, xsu, wu, bu, rbuf, h,
          cur, c, t, emb,
          f1W_g + c*16*DIN, f1b_g + c*16, f2W_g + c*32, f2b_g + c*2,
          f3W_g + c*EE*2, f3b_g + c*EE,
          predW, predB, skipW, skipB, xsg, nv_g, outp);
    }
  }
}

// Round 13
// 2623.728 us; speedup vs baseline: 4.2379x; 4.2379x over previous
//
#include <hip/hip_runtime.h>
#include <hip/hip_fp16.h>
#include <math.h>

#define BB 8
#define TT 12
#define NN 716
#define EE 10
#define HH 64
#define DIN 65
#define OG 128
#define OU 64
#define XSP 68     // padded xs / parts row stride
#define JS 32      // j-split for xg2 gemm
#define JRX 23     // j per split (32*23=736 >= 716)
#define NTN 128    // n-tile in xg2
#define NP 768     // padded n for parts
#define NI4 17     // ceil(DIN/4) i4 slots in w4 layout
#define NVT 768    // nvsT column count (stride)

__device__ __forceinline__ float sigmf(float x){ return 1.0f/(1.0f+__expf(-x)); }

// ---------------- emb precompute + cur0 ----------------
__global__ void k_emb(const float* __restrict__ src, const float* __restrict__ ne,
                      const float* __restrict__ te, const float* __restrict__ de,
                      float* __restrict__ emb, float* __restrict__ cur){
  int idx = blockIdx.x*256 + threadIdx.x;
  if (idx >= BB*TT*NN) return;
  int n = idx % NN; int t = (idx/NN) % TT; int b = idx/(NN*TT);
  const float* s = src + (size_t)idx*3;
  float x = s[0];
  int ti = (int)(s[1]*288.0f);
  int di = (int)(s[2]);
  size_t eo = ((size_t)b*TT + t)*NN*EE + (size_t)n*EE;
  #pragma unroll
  for (int e=0;e<EE;e++)
    emb[eo+e] = ne[n*EE+e]*te[ti*EE+e]*de[di*EE+e];
  cur[((size_t)t*BB + b)*NN + n] = x;   // cur[0][t][b][n]
}

// ---------------- per-layer prep: w4->fp16 (z=0 gate / z=1 update) + misc (z=2) ----------------
__global__ __launch_bounds__(256) void k_prep_all(
    const float* __restrict__ ne, const float* __restrict__ wp_g,
    const float* __restrict__ wp_u, __half* __restrict__ wg4,
    __half* __restrict__ wu4,
    const float* __restrict__ bp_g, const float* __restrict__ bp_u,
    float* __restrict__ bg, float* __restrict__ bu,
    float* __restrict__ h, const float* __restrict__ cur_c,
    const float* __restrict__ f1W, const float* __restrict__ f1b,
    const float* __restrict__ f2W, const float* __restrict__ f2b,
    const float* __restrict__ f3W, const float* __restrict__ f3b,
    const float* __restrict__ emb,
    float* __restrict__ xsg, float* __restrict__ nv)
{
  __shared__ float wps[EE*4*OG];
  int z = blockIdx.z;
  int tid = threadIdx.x;
  if (z < 2){
    const float* wp = z ? wp_u : wp_g;
    __half* w4 = z ? wu4 : wg4;
    int O = z ? OU : OG;
    int ki4 = blockIdx.x;          // 0..33 : k*17+i4
    int nq  = blockIdx.y;          // 0..3
    int k = ki4/NI4, i4 = ki4 - k*NI4;
    for (int idx=tid; idx<EE*4*O; idx+=256){
      int e = idx/(4*O); int rem = idx - e*4*O; int sub = rem/O; int o = rem - sub*O;
      int i = i4*4 + sub;
      wps[idx] = (i<DIN) ? wp[(((size_t)e*2+k)*DIN+i)*O + o] : 0.f;
    }
    __syncthreads();
    int NG = 256/O;
    int o = tid & (O-1), ng = tid / O;
    int n1 = nq*179, n2 = min(NN, n1+179);
    for (int n = n1+ng; n < n2; n += NG){
      float4 a = {0.f,0.f,0.f,0.f};
      #pragma unroll
      for (int e=0;e<EE;e++){
        float nef = ne[n*EE+e];
        a.x += nef*wps[e*4*O + 0*O + o];
        a.y += nef*wps[e*4*O + 1*O + o];
        a.z += nef*wps[e*4*O + 2*O + o];
        a.w += nef*wps[e*4*O + 3*O + o];
      }
      uint2 pack;
      __half* ph = (__half*)&pack;
      ph[0]=__float2half(a.x); ph[1]=__float2half(a.y);
      ph[2]=__float2half(a.z); ph[3]=__float2half(a.w);
      ((uint2*)w4)[((size_t)(n*2+k)*NI4 + i4)*O + o] = pack;
    }
  } else {
    int mt = (blockIdx.x*4 + blockIdx.y)*256 + tid;
    const int MT = 136*256;
    for (int i=mt; i<BB*NN*HH; i+=MT) h[i] = 0.f;
    for (int i=mt; i<NN*OG; i+=MT){
      int o=i&(OG-1), n=i>>7; float a=0.f;
      #pragma unroll
      for (int e=0;e<EE;e++) a += ne[n*EE+e]*bp_g[e*OG+o];
      bg[i]=a;
    }
    for (int i=mt; i<NN*OU; i+=MT){
      int o=i&(OU-1), n=i>>6; float a=0.f;
      #pragma unroll
      for (int e=0;e<EE;e++) a += ne[n*EE+e]*bp_u[e*OU+o];
      bu[i]=a;
    }
    for (int idx=mt; idx<BB*NN; idx+=MT){
      int b=idx/NN, n=idx-b*NN;
      float x = cur_c[(size_t)b*NN + n];   // t = 0
      float* xr = xsg + (size_t)idx*XSP;
      xr[0]=x;
      #pragma unroll
      for (int i2=1;i2<XSP;i2++) xr[i2]=0.f;
      float h1[16];
      #pragma unroll
      for (int k=0;k<16;k++) h1[k]=sigmf(f1b[k]+f1W[k*DIN]*x);
      float h2[2];
      #pragma unroll
      for (int k=0;k<2;k++){
        float s=f2b[k];
        #pragma unroll
        for (int q=0;q<16;q++) s+=f2W[k*16+q]*h1[q];
        h2[k]=sigmf(s);
      }
      #pragma unroll
      for (int e=0;e<EE;e++){
        float xe=f3b[e]+f3W[e*2]*h2[0]+f3W[e*2+1]*h2[1];
        nv[(size_t)idx*EE+e]=tanhf(emb[(((size_t)b*TT+0)*NN+n)*EE+e]*xe);
      }
    }
  }
}

// ---------------- fused d + xg2 gemm, SoA LDS (conflict-free), fp16 parts ----------------
__global__ __launch_bounds__(256) void k_xg2d(
    const float* __restrict__ nv, const float* __restrict__ xs,
    __half* __restrict__ parts, float* __restrict__ dout)
{
  __shared__ __align__(16) float nvsT[EE][NVT];    // 30720 B SoA (stride 768)
  __shared__ __align__(16) float xss[32][XSP];     // 8704 B (unscaled xs rows)
  __shared__ __align__(16) float gs[32][NTN+4];    // 16896 B (d_j-folded G tile)
  __shared__ float dls[32];
  int js = blockIdx.x, b = blockIdx.y;
  int tid = threadIdx.x;
  int j0 = js*JRX;
  int cnt = NN - j0; if (cnt > JRX) cnt = JRX;     // 23 (or 3 for js=31)
  // ---- P0: stage nv -> SoA, zero-pad n in [716,768), stage unscaled xs rows
  {
    const float* nvb = nv + (size_t)b*NN*EE;
    for (int idx=tid; idx<NN*EE; idx+=256){
      int n = idx/EE, e = idx - n*EE;
      nvsT[e][n] = nvb[idx];
    }
    for (int idx=tid; idx<EE*(NVT-NN); idx+=256){
      int e = idx/(NVT-NN), n = NN + (idx - e*(NVT-NN));
      nvsT[e][n] = 0.f;
    }
    for (int idx=tid; idx<32*XSP; idx+=256){
      int r = idx/XSP, ii = idx - r*XSP;
      float v = 0.f;
      if (r < cnt && ii <= 64)
        v = xs[((size_t)b*NN+j0+r)*XSP + ii];
      xss[r][ii] = v;
    }
  }
  __syncthreads();
  // ---- P1: d for this j-range; jg group (4 j's) x 32-lane n stride
  int jg = tid>>5, ns = tid&31;
  float bv[4][EE];
  #pragma unroll
  for (int r=0;r<4;r++){
    int jr = jg*4+r;
    bool ok = (jr < cnt);
    #pragma unroll
    for (int e=0;e<EE;e++) bv[r][e] = ok ? nvsT[e][j0+jr] : 0.f;
  }
  {
    float sums[4]={0.f,0.f,0.f,0.f};
    for (int n=ns; n<NN; n+=32){
      float av[EE];
      #pragma unroll
      for (int e=0;e<EE;e++) av[e] = nvsT[e][n];
      #pragma unroll
      for (int r=0;r<4;r++){
        float s=0.f;
        #pragma unroll
        for (int e=0;e<EE;e++) s += bv[r][e]*av[e];
        sums[r] += fmaxf(s,0.f);
      }
    }
    #pragma unroll
    for (int r=0;r<4;r++){
      float s = sums[r];
      s += __shfl_xor(s,1,64); s += __shfl_xor(s,2,64);
      s += __shfl_xor(s,4,64); s += __shfl_xor(s,8,64);
      s += __shfl_xor(s,16,64);
      sums[r] = s;
    }
    if (ns==0){
      #pragma unroll
      for (int r=0;r<4;r++){
        int jr = jg*4+r;
        if (jr < cnt){
          float dv = rsqrtf(sums[r]);
          dls[jr] = dv;
          dout[b*NN + j0 + jr] = dv;
        }
      }
    }
  }
  __syncthreads();   // dls ready
  float dl[4];
  #pragma unroll
  for (int r=0;r<4;r++){ int jr=jg*4+r; dl[r] = (jr<cnt)? dls[jr] : 0.f; }
  // acc mapping
  int ng = tid >> 3, ig = tid & 7;   // 4 n's at ng*4, 8 i's at ig*8
  // ---- P3: loop n-tiles
  for (int nc=0; nc<6; ++nc){
    int n0 = nc*NTN;
    // G tile: (jg: 4 j's, bv in regs) x (ns + 32k n), d_j folded
    #pragma unroll
    for (int k=0;k<4;k++){
      int n = n0 + ns + 32*k;          // < 768 always (pad zeros)
      float av[EE];
      #pragma unroll
      for (int e=0;e<EE;e++) av[e] = nvsT[e][n];
      #pragma unroll
      for (int r=0;r<4;r++){
        float s=0.f;
        #pragma unroll
        for (int e=0;e<EE;e++) s += bv[r][e]*av[e];
        gs[jg*4+r][ns + 32*k] = fmaxf(s,0.f)*dl[r];
      }
    }
    __syncthreads();   // gs ready
    // acc: 4n x 8i per thread over cnt j's
    {
      float acc[4][8];
      #pragma unroll
      for (int r=0;r<4;r++)
        #pragma unroll
        for (int s2=0;s2<8;s2++) acc[r][s2]=0.f;
      for (int jj=0; jj<cnt; ++jj){
        float4 g4  = *(const float4*)&gs[jj][ng*4];
        float4 x4a = *(const float4*)&xss[jj][ig*8];
        float4 x4b = *(const float4*)&xss[jj][ig*8+4];
        float gr[4] = {g4.x, g4.y, g4.z, g4.w};
        float xr[8] = {x4a.x,x4a.y,x4a.z,x4a.w, x4b.x,x4b.y,x4b.z,x4b.w};
        #pragma unroll
        for (int r=0;r<4;r++)
          #pragma unroll
          for (int s2=0;s2<8;s2++) acc[r][s2] += gr[r]*xr[s2];
      }
      #pragma unroll
      for (int r=0;r<4;r++){
        int n = n0 + ng*4 + r;     // < NP always
        union { __half h[8]; uint2 u[2]; } pk;
        #pragma unroll
        for (int s2=0;s2<8;s2++) pk.h[s2] = __float2half(acc[r][s2]);
        size_t base = (((size_t)js*BB+b)*NP+n)*XSP;
        *(uint2*)&parts[base + ig*8]     = pk.u[0];
        *(uint2*)&parts[base + ig*8 + 4] = pk.u[1];
      }
      if (tid < NTN){
        float s = 0.f;
        for (int jj=0; jj<cnt; ++jj) s += gs[jj][tid]*xss[jj][64];
        parts[(((size_t)js*BB+b)*NP + n0+tid)*XSP + 64] = __float2half(s);
      }
    }
    __syncthreads();   // protect gs rewrite
  }
}

// ---------------- gate transform (fp16 weights + parts, reg-capped) ----------------
__global__ __launch_bounds__(256, 4) void k_tr_gate(
    const __half* __restrict__ wg, const float* __restrict__ bg,
    const __half* __restrict__ parts, const float* __restrict__ d,
    const float* __restrict__ xsg,
    const float* __restrict__ cur_ct, const float* __restrict__ h,
    const float* __restrict__ emb, int t,
    const float* __restrict__ f1W, const float* __restrict__ f1b,
    const float* __restrict__ f2W, const float* __restrict__ f2b,
    const float* __restrict__ f3W, const float* __restrict__ f3b,
    float* __restrict__ rbuf, float* __restrict__ xsu, float* __restrict__ nv)
{
  __shared__ float xg2s[BB][XSP];
  __shared__ float xss[BB][XSP];
  __shared__ float cs[BB][DIN];
  __shared__ float h1s[BB][16];
  __shared__ float h2s[BB][2];
  int n = blockIdx.x;
  int tid = threadIdx.x;
  // vectorized parts reduce: 4 halves per uint2 load
  if (tid < BB*17){
    int b = tid/17, i4 = tid - b*17;
    float s0=0.f,s1=0.f,s2=0.f,s3=0.f;
    const uint2* pbase = (const uint2*)parts;
    #pragma unroll 8
    for (int js2=0; js2<JS; js2++){
      uint2 r = pbase[(((size_t)js2*BB+b)*NP+n)*17 + i4];
      const __half* hp = (const __half*)&r;
      s0 += __half2float(hp[0]); s1 += __half2float(hp[1]);
      s2 += __half2float(hp[2]); s3 += __half2float(hp[3]);
    }
    float dn = d[b*NN+n];
    int i = i4*4;
    if (i4 < 16){
      xg2s[b][i]=s0*dn; xg2s[b][i+1]=s1*dn; xg2s[b][i+2]=s2*dn; xg2s[b][i+3]=s3*dn;
    } else {
      xg2s[b][64]=s0*dn; xg2s[b][65]=0.f; xg2s[b][66]=0.f; xg2s[b][67]=0.f;
    }
  }
  for (int idx=tid; idx<BB*XSP; idx+=256){
    int b = idx/XSP, i = idx - b*XSP;
    xss[b][i] = (i<65) ? xsg[((size_t)b*NN+n)*XSP + i] : 0.f;
  }
  __syncthreads();
  {
    int o = tid & 127, half = tid >> 7;
    const uint2* w0p = (const uint2*)wg + ((size_t)n*2+0)*NI4*OG + o;
    const uint2* w1p = w0p + (size_t)NI4*OG;
    float bgv = bg[n*OG+o];
    float acc[4]; acc[0]=bgv; acc[1]=bgv; acc[2]=bgv; acc[3]=bgv;
    #pragma unroll 2
    for (int i4=0;i4<NI4;i4++){
      uint2 r0 = w0p[(size_t)i4*OG];
      uint2 r1 = w1p[(size_t)i4*OG];
      const __half* h0 = (const __half*)&r0;
      const __half* h1 = (const __half*)&r1;
      float w0x=__half2float(h0[0]), w0y=__half2float(h0[1]),
            w0z=__half2float(h0[2]), w0w=__half2float(h0[3]);
      float w1x=__half2float(h1[0]), w1y=__half2float(h1[1]),
            w1z=__half2float(h1[2]), w1w=__half2float(h1[3]);
      int i = i4*4;
      #pragma unroll
      for (int bb=0;bb<4;bb++){
        int b = 2*bb+half;
        acc[bb] += xss[b][i]*w0x + xss[b][i+1]*w0y
                 + xss[b][i+2]*w0z + xss[b][i+3]*w0w
                 + xg2s[b][i]*w1x + xg2s[b][i+1]*w1y
                 + xg2s[b][i+2]*w1z + xg2s[b][i+3]*w1w;
      }
    }
    #pragma unroll
    for (int bb=0;bb<4;bb++){
      int b = 2*bb+half;
      float v = sigmf(acc[bb]);
      if (o < 64){
        float cv = v * h[((size_t)b*NN+n)*HH + o];
        xsu[((size_t)b*NN+n)*XSP + 1 + o] = cv;
        cs[b][1+o] = cv;
      } else {
        rbuf[((size_t)b*NN+n)*HH + (o-64)] = v;
      }
    }
    if (o == 64){
      #pragma unroll
      for (int bb=0;bb<4;bb++){
        int b = 2*bb+half;
        float x = cur_ct[(size_t)b*NN+n];
        cs[b][0] = x;
        xsu[((size_t)b*NN+n)*XSP] = x;
      }
    }
  }
  __syncthreads();
  if (tid < BB*16){
    int b=tid>>4, k=tid&15;
    const float* wr = f1W + k*DIN;
    float s = f1b[k];
    #pragma unroll
    for (int i=0;i<DIN;i++) s += cs[b][i]*wr[i];
    h1s[b][k] = sigmf(s);
  }
  __syncthreads();
  if (tid < BB*2){
    int b=tid>>1, k=tid&1;
    float s = f2b[k];
    #pragma unroll
    for (int q2=0;q2<16;q2++) s += h1s[b][q2]*f2W[k*16+q2];
    h2s[b][k] = sigmf(s);
  }
  __syncthreads();
  if (tid < BB*EE){
    int b=tid/EE, e=tid-b*EE;
    float xe = f3b[e] + f3W[e*2]*h2s[b][0] + f3W[e*2+1]*h2s[b][1];
    nv[((size_t)b*NN+n)*EE+e] = tanhf(emb[(((size_t)b*TT+t)*NN+n)*EE+e]*xe);
  }
}

// ---------------- update transform (fp16 weights + parts, reg-capped) ----------------
__global__ __launch_bounds__(256, 4) void k_tr_upd(
    const __half* __restrict__ wu, const float* __restrict__ bu,
    const __half* __restrict__ parts, const float* __restrict__ d,
    const float* __restrict__ xsu,
    const float* __restrict__ rbuf, float* __restrict__ h,
    float* __restrict__ cur, int c, int t,
    const float* __restrict__ emb,
    const float* __restrict__ f1W, const float* __restrict__ f1b,
    const float* __restrict__ f2W, const float* __restrict__ f2b,
    const float* __restrict__ f3W, const float* __restrict__ f3b,
    float* __restrict__ xsg, float* __restrict__ nv,
    const float* __restrict__ predW, const float* __restrict__ predB,
    const float* __restrict__ skipW, const float* __restrict__ skipB,
    float* __restrict__ out)
{
  __shared__ float xg2s[BB][XSP];
  __shared__ float xss[BB][XSP];
  __shared__ float hs[BB][HH];
  __shared__ float h1s[BB][16];
  __shared__ float h2s[BB][2];
  __shared__ float xns[BB];
  int n = blockIdx.x;
  int tid = threadIdx.x;
  if (tid < BB*17){
    int b = tid/17, i4 = tid - b*17;
    float s0=0.f,s1=0.f,s2=0.f,s3=0.f;
    const uint2* pbase = (const uint2*)parts;
    #pragma unroll 8
    for (int js2=0; js2<JS; js2++){
      uint2 r = pbase[(((size_t)js2*BB+b)*NP+n)*17 + i4];
      const __half* hp = (const __half*)&r;
      s0 += __half2float(hp[0]); s1 += __half2float(hp[1]);
      s2 += __half2float(hp[2]); s3 += __half2float(hp[3]);
    }
    float dn = d[b*NN+n];
    int i = i4*4;
    if (i4 < 16){
      xg2s[b][i]=s0*dn; xg2s[b][i+1]=s1*dn; xg2s[b][i+2]=s2*dn; xg2s[b][i+3]=s3*dn;
    } else {
      xg2s[b][64]=s0*dn; xg2s[b][65]=0.f; xg2s[b][66]=0.f; xg2s[b][67]=0.f;
    }
  }
  for (int idx=tid; idx<BB*XSP; idx+=256){
    int b = idx/XSP, i = idx - b*XSP;
    xss[b][i] = (i<65) ? xsu[((size_t)b*NN+n)*XSP + i] : 0.f;
  }
  __syncthreads();
  {
    int o = tid & 63, grp = tid >> 6;
    const uint2* w0p = (const uint2*)wu + ((size_t)n*2+0)*NI4*OU + o;
    const uint2* w1p = w0p + (size_t)NI4*OU;
    float acc[2];
    acc[0] = bu[n*OU+o]; acc[1] = acc[0];
    #pragma unroll 2
    for (int i4=0;i4<NI4;i4++){
      uint2 r0 = w0p[(size_t)i4*OU];
      uint2 r1 = w1p[(size_t)i4*OU];
      const __half* h0 = (const __half*)&r0;
      const __half* h1 = (const __half*)&r1;
      float w0x=__half2float(h0[0]), w0y=__half2float(h0[1]),
            w0z=__half2float(h0[2]), w0w=__half2float(h0[3]);
      float w1x=__half2float(h1[0]), w1y=__half2float(h1[1]),
            w1z=__half2float(h1[2]), w1w=__half2float(h1[3]);
      int i = i4*4;
      #pragma unroll
      for (int bb=0;bb<2;bb++){
        int b = grp + 4*bb;
        acc[bb] += xss[b][i]*w0x + xss[b][i+1]*w0y
                 + xss[b][i+2]*w0z + xss[b][i+3]*w0w
                 + xg2s[b][i]*w1x + xg2s[b][i+1]*w1y
                 + xg2s[b][i+2]*w1z + xg2s[b][i+3]*w1w;
      }
    }
    #pragma unroll
    for (int bb=0;bb<2;bb++){
      int b = grp + 4*bb;
      float hc = tanhf(acc[bb]);
      float r = rbuf[((size_t)b*NN+n)*HH+o];
      float hold = h[((size_t)b*NN+n)*HH+o];
      float hn = r*hold + (1.f-r)*hc;
      h[((size_t)b*NN+n)*HH+o] = hn;
      hs[b][o] = hn;
    }
  }
  __syncthreads();
  if (t < TT-1){
    if (tid < BB){
      float x = cur[(((size_t)c*TT + (t+1))*BB + tid)*NN + n];
      xns[tid] = x;
      xsg[((size_t)tid*NN+n)*XSP] = x;
    }
    for (int idx=tid; idx<BB*HH; idx+=256){
      int b = idx>>6, oo = idx&63;
      xsg[((size_t)b*NN+n)*XSP + 1 + oo] = hs[b][oo];
    }
    __syncthreads();
    if (tid < BB*16){
      int b=tid>>4, k=tid&15;
      const float* wr = f1W + k*DIN;
      float s = f1b[k] + wr[0]*xns[b];
      #pragma unroll
      for (int oo=0;oo<HH;oo++) s += hs[b][oo]*wr[1+oo];
      h1s[b][k] = sigmf(s);
    }
    __syncthreads();
    if (tid < BB*2){
      int b=tid>>1, k=tid&1;
      float s = f2b[k];
      #pragma unroll
      for (int q2=0;q2<16;q2++) s += h1s[b][q2]*f2W[k*16+q2];
      h2s[b][k] = sigmf(s);
    }
    __syncthreads();
    if (tid < BB*EE){
      int b=tid/EE, e=tid-b*EE;
      float xe = f3b[e] + f3W[e*2]*h2s[b][0] + f3W[e*2+1]*h2s[b][1];
      nv[((size_t)b*NN+n)*EE+e] =
        tanhf(emb[(((size_t)b*TT+(t+1))*NN+n)*EE+e]*xe);
    }
  } else {
    if (tid < BB*TT){
      int b = tid/TT, ot = tid - b*TT;
      const float* pw = predW + ((size_t)c*TT + ot)*HH;
      float pv = predB[c*TT+ot];
      #pragma unroll
      for (int q2=0;q2<HH;q2++) pv += hs[b][q2]*pw[q2];
      size_t oi = ((size_t)b*TT+ot)*NN + n;
      if (c == 0){
        out[oi] = pv;
        const float* sw = skipW + (size_t)ot*HH;
        float sk = skipB[ot];
        #pragma unroll
        for (int q2=0;q2<HH;q2++) sk += hs[b][q2]*sw[q2];
        cur[(((size_t)TT+ot)*BB + b)*NN + n] =
            cur[((size_t)ot*BB + b)*NN + n] - sk;
      } else {
        out[oi] += pv;
      }
    }
  }
}

extern "C" void kernel_launch(void* const* d_in, const int* in_sizes, int n_in,
                              void* d_out, int out_size, void* d_ws, size_t ws_size,
                              hipStream_t stream){
  const float* src  = (const float*)d_in[0];
  const float* ne   = (const float*)d_in[1];
  const float* te   = (const float*)d_in[2];
  const float* de   = (const float*)d_in[3];
  const float* wp_g = (const float*)d_in[4];
  const float* bp_g = (const float*)d_in[5];
  const float* f1W_g= (const float*)d_in[6];
  const float* f1b_g= (const float*)d_in[7];
  const float* f2W_g= (const float*)d_in[8];
  const float* f2b_g= (const float*)d_in[9];
  const float* f3W_g= (const float*)d_in[10];
  const float* f3b_g= (const float*)d_in[11];
  const float* wp_u = (const float*)d_in[12];
  const float* bp_u = (const float*)d_in[13];
  const float* f1W_u= (const float*)d_in[14];
  const float* f1b_u= (const float*)d_in[15];
  const float* f2W_u= (const float*)d_in[16];
  const float* f2b_u= (const float*)d_in[17];
  const float* f3W_u= (const float*)d_in[18];
  const float* f3b_u= (const float*)d_in[19];
  const float* predW= (const float*)d_in[20];
  const float* predB= (const float*)d_in[21];
  const float* skipW= (const float*)d_in[22];
  const float* skipB= (const float*)d_in[23];

  float* ws   = (float*)d_ws;
  float* emb  = ws;
  float* cur  = emb  + (size_t)BB*TT*NN*EE;
  float* wgf  = cur  + (size_t)2*TT*BB*NN;               // fp16 region (half count/2 floats)
  float* bg   = wgf  + (size_t)NN*2*NI4*OG*4/2;
  float* wuf  = bg   + (size_t)NN*OG;
  float* bu   = wuf  + (size_t)NN*2*NI4*OU*4/2;
  float* h    = bu   + (size_t)NN*OU;
  float* xsg  = h    + (size_t)BB*NN*HH;
  float* xsu  = xsg  + (size_t)BB*NN*XSP;
  float* nv   = xsu  + (size_t)BB*NN*XSP;
  float* dbuf = nv   + (size_t)BB*NN*EE;
  float* partsf = dbuf + (size_t)BB*NN;                  // fp16 region
  float* rbuf = partsf + (size_t)JS*BB*NP*XSP/2;
  float* outp = (float*)d_out;
  __half* wg    = (__half*)wgf;
  __half* wu    = (__half*)wuf;
  __half* parts = (__half*)partsf;

  k_emb<<<(BB*TT*NN+255)/256, 256, 0, stream>>>(src, ne, te, de, emb, cur);

  for (int c=0;c<2;c++){
    k_prep_all<<<dim3(2*NI4,4,3),256,0,stream>>>(ne,
        wp_g + (size_t)c*EE*2*DIN*OG, wp_u + (size_t)c*EE*2*DIN*OU, wg, wu,
        bp_g + (size_t)c*EE*OG, bp_u + (size_t)c*EE*OU, bg, bu,
        h, cur + (size_t)c*TT*BB*NN,
        f1W_g + c*16*DIN, f1b_g + c*16, f2W_g + c*32, f2b_g + c*2,
        f3W_g + c*EE*2, f3b_g + c*EE, emb, xsg, nv);
    for (int t=0;t<TT;t++){
      k_xg2d<<<dim3(JS,BB),256,0,stream>>>(nv, xsg, parts, dbuf);
      k_tr_gate<<<NN,256,0,stream>>>(wg, bg, parts, dbuf, xsg,
          cur + ((size_t)c*TT+t)*BB*NN, h, emb, t,
          f1W_u + c*16*DIN, f1b_u + c*16, f2W_u + c*32, f2b_u + c*2,
          f3W_u + c*EE*2, f3b_u + c*EE, rbuf, xsu, nv);
      k_xg2d<<<dim3(JS,BB),256,0,stream>>>(nv, xsu, parts, dbuf);
      k_tr_upd<<<NN,256,0,stream>>>(wu, bu, parts, dbuf, xsu, rbuf, h,
          cur, c, t, emb,
          f1W_g + c*16*DIN, f1b_g + c*16, f2W_g + c*32, f2b_g + c*2,
          f3W_g + c*EE*2, f3b_g + c*EE,
          xsg, nv, predW, predB, skipW, skipB, outp);
    }
  }
}